// Round 9
// baseline (148.231 us; speedup 1.0000x reference)
//
#include <hip/hip_runtime.h>
#include <hip/hip_bf16.h>
#include <stdint.h>

// GPT-2 prefill attention: B=2, S=2048, D=1024, H=16, hd=64.
// cvt/transpose prepass -> QKV GEMM (256^2 8-phase counted-vmcnt, m201 template)
// -> v transpose -> bias tiling -> flash attn (32x32 swapped-QK^T) -> proj GEMM.

typedef __attribute__((ext_vector_type(4))) float f32x4;
typedef __attribute__((ext_vector_type(16))) float f32x16;
typedef __attribute__((ext_vector_type(8))) short s16x8;
typedef __attribute__((ext_vector_type(4))) short s16x4;
typedef unsigned short u16;

#define LOG2E 1.4426950408889634f
#define QSCALE 0.18033688011112042f  // 0.125 * LOG2E

__device__ __forceinline__ u16 f2bf(float f) {
  unsigned w;
  asm("v_cvt_pk_bf16_f32 %0, %1, %2" : "=v"(w) : "v"(f), "v"(f));
  return (u16)w;
}
__device__ __forceinline__ unsigned cvtpk(float lo, float hi) {
  unsigned w;
  asm("v_cvt_pk_bf16_f32 %0, %1, %2" : "=v"(w) : "v"(lo), "v"(hi));
  return w;
}
__device__ __forceinline__ float bf2f(u16 h) {
  unsigned int x = ((unsigned int)h) << 16;
  return __builtin_bit_cast(float, x);
}
__device__ __forceinline__ float fexp2(float x) {   // raw v_exp_f32 (log2 domain)
  float r;
  asm("v_exp_f32 %0, %1" : "=v"(r) : "v"(x));
  return r;
}
__device__ __forceinline__ void pl32swap(unsigned& a, unsigned& b) {
  asm volatile("v_permlane32_swap_b32 %0, %1" : "+v"(a), "+v"(b));
}
__device__ __forceinline__ s16x8 frag8(unsigned a, unsigned b, unsigned c, unsigned d) {
  union { unsigned u[4]; s16x8 v; } t;
  t.u[0] = a; t.u[1] = b; t.u[2] = c; t.u[3] = d;
  return t.v;
}
__device__ __forceinline__ f32x16 mfma32(s16x8 a, s16x8 b, f32x16 c) {
  return __builtin_amdgcn_mfma_f32_32x32x16_bf16(a, b, c, 0, 0, 0);
}

__device__ __forceinline__ void gload_lds16(const u16* g, u16* lds) {
  __builtin_amdgcn_global_load_lds(
      (const __attribute__((address_space(1))) unsigned int*)g,
      (__attribute__((address_space(3))) unsigned int*)lds, 16, 0, 0);
}

// ---------------- prepass kernels ----------------

__global__ __launch_bounds__(256) void cvt_f32_bf16(const float* __restrict__ x,
                                                    u16* __restrict__ y, int n4) {
  int i = blockIdx.x * 256 + threadIdx.x;
  if (i < n4) {
    f32x4 v = *(const f32x4*)&x[(size_t)i * 4];
    s16x4 o;
    o[0] = (short)f2bf(v[0]); o[1] = (short)f2bf(v[1]);
    o[2] = (short)f2bf(v[2]); o[3] = (short)f2bf(v[3]);
    *(s16x4*)&y[(size_t)i * 4] = o;
  }
}

// W[K][N] f32 -> WT[N][K] bf16
__global__ __launch_bounds__(256) void transpose_w_bf16(const float* __restrict__ W,
                                                        u16* __restrict__ WT,
                                                        int K, int N) {
  __shared__ float tile[32][33];
  const int n0 = blockIdx.x * 32, k0 = blockIdx.y * 32;
  const int tx = threadIdx.x & 31, ty = threadIdx.x >> 5;
#pragma unroll
  for (int i = 0; i < 32; i += 8)
    tile[ty + i][tx] = W[(size_t)(k0 + ty + i) * N + (n0 + tx)];
  __syncthreads();
#pragma unroll
  for (int i = 0; i < 32; i += 8)
    WT[(size_t)(n0 + ty + i) * K + (k0 + tx)] = f2bf(tile[tx][ty + i]);
}

// v_ws [bh][s][d] bf16 -> vT_ws [bh][d][s] bf16, 64x64 LDS tiles
__global__ __launch_bounds__(256) void transpose_v(const u16* __restrict__ v,
                                                   u16* __restrict__ vT) {
  __shared__ u16 tile[64][72];   // +8 pad
  const int bh = blockIdx.y;
  const int s0 = blockIdx.x * 64;
  const int tr = threadIdx.x >> 2, tc = (threadIdx.x & 3) * 16;
  const u16* src = v + (size_t)bh * 131072u + (size_t)(s0 + tr) * 64 + tc;
  *(s16x8*)&tile[tr][tc] = *(const s16x8*)src;
  *(s16x8*)&tile[tr][tc + 8] = *(const s16x8*)(src + 8);
  __syncthreads();
  u16 o[16];
#pragma unroll
  for (int x = 0; x < 16; x++) o[x] = tile[tc + x][tr];
  u16* dst = vT + (size_t)bh * 131072u + (size_t)tr * 2048 + s0 + tc;
  *(s16x8*)dst = *(s16x8*)&o[0];
  *(s16x8*)(dst + 8) = *(s16x8*)&o[8];
}

// bias -> packed triangular table in the 32x32 MFMA C/D register layout, *LOG2E,
// causal mask folded as -inf.
__global__ __launch_bounds__(128) void bias_tile(const float* __restrict__ B,
                                                 u16* __restrict__ T) {
  const int kt = blockIdx.x;      // 0..31
  const int q32 = blockIdx.y;     // 0..63
  if (kt > (q32 >> 1)) return;
  const int t = threadIdx.x >> 6, lane = threadIdx.x & 63;
  const int hh = q32 >> 1;
  const size_t boff = (size_t)(hh + (q32 & 1)) * (hh + 1);
  const int q = q32 * 32 + (lane & 31);
  const int kb = kt * 64 + t * 32 + 4 * (lane >> 5);
  u16 v[16];
#pragma unroll
  for (int r = 0; r < 16; r++) {
    const int k = kb + (r & 3) + 8 * (r >> 2);
    v[r] = (k <= q) ? f2bf(B[(size_t)q * 2048 + k] * LOG2E) : (u16)0xFF80;
  }
  u16* dst = T + (boff + kt) * 2048 + t * 1024 + (size_t)lane * 16;
  *(s16x8*)dst = *(s16x8*)&v[0];
  *(s16x8*)(dst + 8) = *(s16x8*)&v[8];
}

// ---------------- QKV GEMM: 256^2 tile, BK=64, 8 waves, 8-phase counted-vmcnt ----
// m201 template port. M=4096, N=3072, K=1024 hardcoded. 4 phases per K-tile:
// each phase stages ONE half-tile (2 x global_load_lds) and computes ONE C-quadrant
// (16 MFMA). vmcnt(2) only at tile boundary (never 0 mid-loop); raw s_barrier;
// lgkmcnt(0)+sched_barrier before MFMA; T2 XOR chunk-swizzle; T5 setprio.

__global__ __launch_bounds__(512, 2) void gemm_qkv8(
    const u16* __restrict__ A, const u16* __restrict__ BT,
    const float* __restrict__ bias, float* __restrict__ outF,
    u16* __restrict__ q_ws, u16* __restrict__ k_ws, u16* __restrict__ v_ws) {
  __shared__ u16 As[2][256 * 64];   // 64KB
  __shared__ u16 Bs[2][256 * 64];   // 64KB

  const int flat0 = blockIdx.x;                    // 192 blocks
  const int flat = (flat0 & 7) * 24 + (flat0 >> 3); // bijective XCD swizzle
  const int m0 = (flat / 12) * 256;
  const int n0 = (flat % 12) * 256;

  const int tid = threadIdx.x;
  const int wid = tid >> 6, lane = tid & 63;
  const int c16 = lane & 15, hi4 = lane >> 4;
  const int wm = wid >> 2, wn = wid & 3;           // 2M x 4N waves, wave tile 128x64

  // staging decomposition: one call = 64 rows (512 lanes x 16B = 8KB).
  // row = H*128 + L*64 + wid*8 + (lane>>3); dest LDS chunk = lane&7;
  // source chunk = (lane&7) ^ (row&7) = (lane&7) ^ (lane>>3)  [pre-swizzle]
  const int srow = wid * 8 + (lane >> 3);          // 0..63
  const int sch = ((lane & 7) ^ (lane >> 3)) * 8;  // u16 units

#define STGA(S, KT, H)                                                          \
  gload_lds16(&A[(size_t)(m0 + (H) * 128 + srow) * 1024 + (KT) * 64 + sch],     \
              &As[S][(H) * 8192 + wid * 512]);                                  \
  gload_lds16(&A[(size_t)(m0 + (H) * 128 + 64 + srow) * 1024 + (KT) * 64 + sch],\
              &As[S][(H) * 8192 + 4096 + wid * 512]);
#define STGB(S, KT, H)                                                          \
  gload_lds16(&BT[(size_t)(n0 + (H) * 128 + srow) * 1024 + (KT) * 64 + sch],    \
              &Bs[S][(H) * 8192 + wid * 512]);                                  \
  gload_lds16(&BT[(size_t)(n0 + (H) * 128 + 64 + srow) * 1024 + (KT) * 64 + sch],\
              &Bs[S][(H) * 8192 + 4096 + wid * 512]);

  f32x4 acc[8][4] = {};

  // prologue: stage tile 0 fully (8 loads/thread)
  STGA(0, 0, 0); STGA(0, 0, 1); STGB(0, 0, 0); STGB(0, 0, 1);

  const int ch0 = (hi4 ^ (c16 & 7)) * 8;           // ks=0 read chunk
  const int ch1 = ((4 + hi4) ^ (c16 & 7)) * 8;     // ks=1 read chunk
  const int arow = wm * 128 + c16;                 // A frag base row
  const int brow = wn * 64 + c16;                  // B frag base row

  s16x8 af[4], bfr[4];

#define DSRD_B(CH)                                                              \
  _Pragma("unroll")                                                             \
  for (int j = 0; j < 4; j++)                                                   \
    bfr[j] = *(const s16x8*)&bs[(brow + j * 16) * 64 + (CH)];
#define DSRD_A(ILO, CH)                                                         \
  _Pragma("unroll")                                                             \
  for (int i = 0; i < 4; i++)                                                   \
    af[i] = *(const s16x8*)&as[(arow + ((ILO) + i) * 16) * 64 + (CH)];
#define MFMA16(IB)                                                              \
  __builtin_amdgcn_s_setprio(1);                                                \
  _Pragma("unroll")                                                             \
  for (int i = 0; i < 4; i++)                                                   \
    _Pragma("unroll")                                                           \
    for (int j = 0; j < 4; j++)                                                 \
      acc[(IB) + i][j] =                                                        \
          __builtin_amdgcn_mfma_f32_16x16x32_bf16(af[i], bfr[j], acc[(IB)+i][j],\
                                                  0, 0, 0);                     \
  __builtin_amdgcn_s_setprio(0);
#define LGKM0                                                                   \
  asm volatile("s_waitcnt lgkmcnt(0)" ::: "memory");                            \
  __builtin_amdgcn_sched_barrier(0);

  for (int t = 0; t < 16; ++t) {
    const int cur = t & 1, nxt = cur ^ 1;
    const u16* as = &As[cur][0];
    const u16* bs = &Bs[cur][0];

    // ---- phase 0: stage A-half0(t+1); tile-boundary counted drain; quad (i0-3, ks0)
    if (t < 15) { STGA(nxt, t + 1, 0); }
    if (t < 15) { asm volatile("s_waitcnt vmcnt(2)" ::: "memory"); }
    else        { asm volatile("s_waitcnt vmcnt(0)" ::: "memory"); }
    __builtin_amdgcn_s_barrier();
    DSRD_B(ch0); DSRD_A(0, ch0);
    __builtin_amdgcn_s_barrier();
    LGKM0; MFMA16(0);
    __builtin_amdgcn_s_barrier();

    // ---- phase 1: stage A-half1(t+1); quad (i4-7, ks0), reuse bfr
    if (t < 15) { STGA(nxt, t + 1, 1); }
    DSRD_A(4, ch0);
    __builtin_amdgcn_s_barrier();
    LGKM0; MFMA16(4);
    __builtin_amdgcn_s_barrier();

    // ---- phase 2: stage B-half0(t+1); quad (i0-3, ks1)
    if (t < 15) { STGB(nxt, t + 1, 0); }
    DSRD_B(ch1); DSRD_A(0, ch1);
    __builtin_amdgcn_s_barrier();
    LGKM0; MFMA16(0);
    __builtin_amdgcn_s_barrier();

    // ---- phase 3: stage B-half1(t+1); quad (i4-7, ks1)
    if (t < 15) { STGB(nxt, t + 1, 1); }
    DSRD_A(4, ch1);
    __builtin_amdgcn_s_barrier();
    LGKM0; MFMA16(4);
    __builtin_amdgcn_s_barrier();
  }
#undef STGA
#undef STGB
#undef DSRD_A
#undef DSRD_B
#undef MFMA16
#undef LGKM0

  // epilogue: scatter q/k/v (which is block-uniform: 256-col tiles never straddle 1024)
  const int which = n0 >> 10;            // 0=q 1=k 2=v
#pragma unroll
  for (int i = 0; i < 8; i++) {
#pragma unroll
    for (int j = 0; j < 4; j++) {
      const int col = n0 + wn * 64 + j * 16 + c16;
      const int rb = m0 + wm * 128 + i * 16 + hi4 * 4;
      const float bv = bias[col];
      const int h = (col >> 6) & 15, d = col & 63;
#pragma unroll
      for (int u = 0; u < 4; u++) {
        const int r = rb + u;
        const int b = r >> 11, s = r & 2047;
        const size_t idx = (size_t)(b * 16 + h) * 131072u + (size_t)s * 64 + d;
        const float v = acc[i][j][u] + bv;
        if (which == 0) {
          q_ws[idx] = f2bf(v * QSCALE);     // fold 1/sqrt(hd) * LOG2E
        } else if (which == 1) {
          outF[4194304u + idx] = v;
          k_ws[idx] = f2bf(v);
        } else {
          outF[8388608u + idx] = v;
          v_ws[idx] = f2bf(v);              // row-major; transposed later
        }
      }
    }
  }
}

// ---------------- proj GEMM: 128^2 double-buffered (round-8, verified) ----------

__global__ __launch_bounds__(256) void gemm_bt(
    const u16* __restrict__ A, const u16* __restrict__ BT,
    const float* __restrict__ bias, float* __restrict__ outF,
    int M, int N, int K) {
  __shared__ u16 As[2][128 * 32];
  __shared__ u16 Bs[2][128 * 32];
  const int nwg = gridDim.x * gridDim.y;
  int flat = blockIdx.y * gridDim.x + blockIdx.x;
  flat = (flat & 7) * (nwg >> 3) + (flat >> 3);
  const int m0 = (flat / gridDim.x) * 128, n0 = (flat % gridDim.x) * 128;
  const int tid = threadIdx.x;
  const int wid = tid >> 6, lane = tid & 63;
  const int c = lane & 15, hi = lane >> 4;
  const int wm = wid >> 1, wn = wid & 1;
  const int srow = lane >> 2;
  const int skp = (lane & 3) * 8;

  f32x4 acc[4][4] = {};

#define STG(SLOT, K0)                                                         \
  {                                                                           \
    _Pragma("unroll")                                                         \
    for (int t = 0; t < 2; t++) {                                             \
      const int rowl = wid * 32 + t * 16;                                     \
      gload_lds16(&A[(size_t)(m0 + rowl + srow) * K + (K0) + skp],            \
                  &As[SLOT][rowl * 32]);                                      \
      gload_lds16(&BT[(size_t)(n0 + rowl + srow) * K + (K0) + skp],           \
                  &Bs[SLOT][rowl * 32]);                                      \
    }                                                                         \
  }

  STG(0, 0);
  __syncthreads();

  int bufi = 0;
  for (int k0 = 0; k0 < K; k0 += 32) {
    if (k0 + 32 < K) {
      if (bufi) { STG(0, k0 + 32); } else { STG(1, k0 + 32); }
    }
    s16x8 af[4], bfr[4];
#pragma unroll
    for (int i = 0; i < 4; i++)
      af[i] = *(const s16x8*)&As[bufi][(wm * 64 + i * 16 + c) * 32 + hi * 8];
#pragma unroll
    for (int i = 0; i < 4; i++)
      bfr[i] = *(const s16x8*)&Bs[bufi][(wn * 64 + i * 16 + c) * 32 + hi * 8];
    __builtin_amdgcn_s_setprio(1);
#pragma unroll
    for (int i = 0; i < 4; i++)
#pragma unroll
      for (int j = 0; j < 4; j++)
        acc[i][j] = __builtin_amdgcn_mfma_f32_16x16x32_bf16(af[i], bfr[j], acc[i][j], 0, 0, 0);
    __builtin_amdgcn_s_setprio(0);
    __syncthreads();
    bufi ^= 1;
  }
#undef STG

#pragma unroll
  for (int i = 0; i < 4; i++) {
#pragma unroll
    for (int j = 0; j < 4; j++) {
      const int col = n0 + wn * 64 + j * 16 + c;
      const int rb = m0 + wm * 64 + i * 16 + hi * 4;
      const float bv = bias[col];
#pragma unroll
      for (int u = 0; u < 4; u++)
        outF[(size_t)(rb + u) * N + col] = acc[i][j][u] + bv;
    }
  }
}

// ---------------- fused causal attention (round-6, verified) ----------------

__global__ __launch_bounds__(256, 4) void attn_fused(
    const u16* __restrict__ q_ws, const u16* __restrict__ k_ws,
    const u16* __restrict__ vT_ws, const u16* __restrict__ biasT,
    u16* __restrict__ ctx) {
  __shared__ u16 Ks[2][64 * 64];
  __shared__ u16 Vs[2][64 * 64];

  const int id = blockIdx.x;
  const int bh = (id & 7) * 4 + ((id >> 3) & 3);
  const int j = id >> 5, j0 = j & 7, sg = j >> 3;
  const int qblk = (sg == 0) ? j0 : (sg == 1) ? (15 - j0)
                 : (sg == 2) ? (16 + j0) : (31 - j0);

  const int wid = threadIdx.x >> 6, lane = threadIdx.x & 63;
  const int pq = wid >> 1, par = wid & 1;
  const int l31 = lane & 31, hi5 = lane >> 5;
  const int qrow0 = qblk * 64 + pq * 32;

  const u16* qh = q_ws + (size_t)bh * 131072u;
  const u16* kh = k_ws + (size_t)bh * 131072u;
  const u16* vh = vT_ws + (size_t)bh * 131072u;

  s16x8 qf[4];
#pragma unroll
  for (int s = 0; s < 4; s++)
    qf[s] = *(const s16x8*)&qh[(size_t)(qrow0 + l31) * 64 + s * 16 + hi5 * 8];

  const int q32 = qblk * 2 + pq;
  const int hh = q32 >> 1;
  const size_t boff = (size_t)(hh + (q32 & 1)) * (hh + 1);
  const u16* bbase = biasT + boff * 2048 + (size_t)par * 1024 + (size_t)lane * 16;

  const int sl_r = lane >> 3, sl_c = lane & 7;

  f32x16 o0 = {}, o1 = {};
  float mrow = -1e30f, lpart = 0.f;

#define STAGE(BUF, N0)                                                        \
  {                                                                           \
    _Pragma("unroll")                                                         \
    for (int t = 0; t < 2; t++) {                                             \
      const int rb = wid * 16 + t * 8;                                        \
      const int r = rb + sl_r;                                                \
      gload_lds16(&kh[(size_t)((N0) + r) * 64 + ((sl_c ^ (r & 7)) * 8)],      \
                  &Ks[BUF][rb * 64]);                                         \
      gload_lds16(&vh[(size_t)r * 2048 + (N0) + ((sl_c ^ (r & 7)) * 8)],      \
                  &Vs[BUF][rb * 64]);                                         \
    }                                                                         \
  }

  STAGE(0, 0);
  __syncthreads();

  int buf = 0;
  const int nkt = qblk + 1;
  const int swz = l31 & 7;
  const int arow = par * 32 + l31;

  s16x8 bc0 = *(const s16x8*)(bbase);
  s16x8 bc1 = *(const s16x8*)(bbase + 8);

  for (int kt = 0; kt < nkt; ++kt) {
    if (kt + 1 < nkt) {
      if (buf) { STAGE(0, kt * 64 + 64); } else { STAGE(1, kt * 64 + 64); }
    }
    const u16* btn = bbase + (size_t)((kt + 1 < nkt) ? kt + 1 : kt) * 2048;
    const s16x8 bn0 = *(const s16x8*)(btn);
    const s16x8 bn1 = *(const s16x8*)(btn + 8);

    f32x16 s0;
#pragma unroll
    for (int r = 0; r < 8; r++) {
      s0[r] = bf2f((u16)bc0[r]);
      s0[r + 8] = bf2f((u16)bc1[r]);
    }

    const u16* ksb = &Ks[buf][0];
    __builtin_amdgcn_s_setprio(1);
#pragma unroll
    for (int s = 0; s < 4; s++) {
      const int chq = ((s * 2 + hi5) ^ swz) * 8;
      const s16x8 a0 = *(const s16x8*)&ksb[arow * 64 + chq];
      s0 = mfma32(a0, qf[s], s0);
    }
    __builtin_amdgcn_s_setprio(0);

    float t0 = fmaxf(fmaxf(s0[0], s0[1]), fmaxf(s0[2], s0[3]));
    float t1 = fmaxf(fmaxf(s0[4], s0[5]), fmaxf(s0[6], s0[7]));
    float t2 = fmaxf(fmaxf(s0[8], s0[9]), fmaxf(s0[10], s0[11]));
    float t3 = fmaxf(fmaxf(s0[12], s0[13]), fmaxf(s0[14], s0[15]));
    float tm = fmaxf(fmaxf(t0, t1), fmaxf(t2, t3));
    tm = fmaxf(tm, __shfl_xor(tm, 32));

    if (__any(tm > mrow + 8.f)) {
      const float nm = fmaxf(mrow, tm);
      const float al = fexp2(mrow - nm);
      mrow = nm;
      lpart *= al;
#pragma unroll
      for (int r = 0; r < 16; r++) { o0[r] *= al; o1[r] *= al; }
    }

    float a0s = 0.f, a1s = 0.f;
#pragma unroll
    for (int r = 0; r < 8; r++) {
      s0[r] = fexp2(s0[r] - mrow);       a0s += s0[r];
      s0[r + 8] = fexp2(s0[r + 8] - mrow); a1s += s0[r + 8];
    }
    lpart += a0s + a1s;

    unsigned wv0 = cvtpk(s0[0], s0[1]),   wv1 = cvtpk(s0[2], s0[3]);
    unsigned wv2 = cvtpk(s0[4], s0[5]),   wv3 = cvtpk(s0[6], s0[7]);
    unsigned wv4 = cvtpk(s0[8], s0[9]),   wv5 = cvtpk(s0[10], s0[11]);
    unsigned wv6 = cvtpk(s0[12], s0[13]), wv7 = cvtpk(s0[14], s0[15]);
    pl32swap(wv0, wv2); pl32swap(wv1, wv3);
    pl32swap(wv4, wv6); pl32swap(wv5, wv7);

    const u16* vsb = &Vs[buf][0];
    __builtin_amdgcn_s_setprio(1);
#pragma unroll
    for (int hf = 0; hf < 2; hf++) {
      const s16x8 pa = hf ? frag8(wv4, wv5, wv6, wv7) : frag8(wv0, wv1, wv2, wv3);
      const int s = par * 2 + hf;
      const int chv = ((s * 2 + hi5) ^ swz) * 8;
      const s16x8 v0 = *(const s16x8*)&vsb[l31 * 64 + chv];
      const s16x8 v1 = *(const s16x8*)&vsb[(32 + l31) * 64 + chv];
      o0 = mfma32(pa, v0, o0);
      o1 = mfma32(pa, v1, o1);
    }
    __builtin_amdgcn_s_setprio(0);

    __syncthreads();
    buf ^= 1;
    bc0 = bn0; bc1 = bn1;
  }
#undef STAGE

  lpart += __shfl_xor(lpart, 32);

  float* obuf = (float*)&Ks[0][0];     // [32 reg][128 slot] f32 = 16KB
  float2* mlb = (float2*)&Vs[0][0];    // [(par*2+pq)*64 + q] -> (m, l)

  __syncthreads();
  if (hi5 == 0) mlb[(par * 2 + pq) * 64 + l31] = make_float2(mrow, lpart);
  if (par == 1) {
    const int slot = pq * 64 + lane;
#pragma unroll
    for (int r = 0; r < 16; r++) {
      obuf[r * 128 + slot] = o0[r];
      obuf[(16 + r) * 128 + slot] = o1[r];
    }
  }
  __syncthreads();
  if (par == 0) {
    const int slot = pq * 64 + lane;
    const int b = bh >> 4, h = bh & 15;
#pragma unroll
    for (int r = 0; r < 16; r++) {
      const int qloc = (r & 3) + 8 * (r >> 2) + 4 * hi5;
      const float2 Aml = mlb[pq * 64 + qloc];
      const float2 Bml = mlb[(2 + pq) * 64 + qloc];
      const float mm = fmaxf(Aml.x, Bml.x);
      const float fa = fexp2(Aml.x - mm), fb = fexp2(Bml.x - mm);
      const float inv = __builtin_amdgcn_rcpf(Aml.y * fa + Bml.y * fb);
      const float om0 = (o0[r] * fa + obuf[r * 128 + slot] * fb) * inv;
      const float om1 = (o1[r] * fa + obuf[(16 + r) * 128 + slot] * fb) * inv;
      const int tok = b * 2048 + qrow0 + qloc;
      ctx[(size_t)tok * 1024 + h * 64 + l31] = f2bf(om0);
      ctx[(size_t)tok * 1024 + h * 64 + 32 + l31] = f2bf(om1);
    }
  }
}

// ---------------- launch ----------------

extern "C" void kernel_launch(void* const* d_in, const int* in_sizes, int n_in,
                              void* d_out, int out_size, void* d_ws, size_t ws_size,
                              hipStream_t stream) {
  const float* hs        = (const float*)d_in[0];  // [2,2048,1024]
  const float* c_attn_w  = (const float*)d_in[1];  // [1024,3072]
  const float* c_attn_b  = (const float*)d_in[2];  // [3072]
  const float* attn_bias = (const float*)d_in[3];  // [2048,2048]
  const float* c_proj_w  = (const float*)d_in[4];  // [1024,1024]
  const float* c_proj_b  = (const float*)d_in[5];  // [1024]
  float* out = (float*)d_out;  // out(4M) | k(4M) | v(4M)

  uint8_t* ws = (uint8_t*)d_ws;
  u16* hsb    = (u16*)(ws + 0);           // 8MB [4096][1024] bf16 (reused for biasT, 4.3MB)
  u16* wqkvT  = (u16*)(ws + 8388608u);    // 6MB [3072][1024] bf16
  u16* wprojT = (u16*)(ws + 14680064u);   // 2MB [1024][1024] bf16
  u16* q_ws   = (u16*)(ws + 16777216u);   // 8MB [B,H,S,hd] bf16 (q * QSCALE)
  u16* k_ws   = (u16*)(ws + 25165824u);   // 8MB [B,H,S,hd] bf16
  u16* vT_ws  = (u16*)(ws + 33554432u);   // 8MB [B,H,hd,S] bf16
  u16* ctx    = (u16*)(ws + 41943040u);   // 8MB [4096][1024] bf16 (also v_ws row-major)
  u16* v_ws   = ctx;                      // v row-major staging; consumed by transpose_v
  u16* biasT  = hsb;                      // overlays hsb after gemm_qkv8

  cvt_f32_bf16<<<4096, 256, 0, stream>>>(hs, hsb, 1048576);
  transpose_w_bf16<<<dim3(96, 32), 256, 0, stream>>>(c_attn_w, wqkvT, 1024, 3072);
  transpose_w_bf16<<<dim3(32, 32), 256, 0, stream>>>(c_proj_w, wprojT, 1024, 1024);

  gemm_qkv8<<<dim3(192), 512, 0, stream>>>(hsb, wqkvT, c_attn_b, out,
                                           q_ws, k_ws, v_ws);

  transpose_v<<<dim3(32, 32), 256, 0, stream>>>(v_ws, vT_ws);

  bias_tile<<<dim3(32, 64), 128, 0, stream>>>(attn_bias, biasT);

  attn_fused<<<dim3(1024), 256, 0, stream>>>(q_ws, k_ws, vT_ws, biasT, ctx);

  gemm_bt<<<dim3(8, 32), 256, 0, stream>>>(ctx, wprojT, c_proj_b, out,
                                           4096, 1024, 1024);
}

// Round 10
// 143.835 us; speedup vs baseline: 1.0306x; 1.0306x over previous
//
#include <hip/hip_runtime.h>
#include <hip/hip_bf16.h>
#include <stdint.h>

// GPT-2 prefill attention: B=2, S=2048, D=1024, H=16, hd=64.
// cvt/transpose prepass -> QKV GEMM (128^2 double-buffered) -> v transpose
// -> f32 bias tiling -> flash attn (paired q-tiles, uniform 33 units/block) -> proj GEMM.

typedef __attribute__((ext_vector_type(4))) float f32x4;
typedef __attribute__((ext_vector_type(16))) float f32x16;
typedef __attribute__((ext_vector_type(8))) short s16x8;
typedef __attribute__((ext_vector_type(4))) short s16x4;
typedef unsigned short u16;

#define LOG2E 1.4426950408889634f
#define QSCALE 0.18033688011112042f  // 0.125 * LOG2E

__device__ __forceinline__ u16 f2bf(float f) {
  unsigned w;
  asm("v_cvt_pk_bf16_f32 %0, %1, %2" : "=v"(w) : "v"(f), "v"(f));
  return (u16)w;
}
__device__ __forceinline__ unsigned cvtpk(float lo, float hi) {
  unsigned w;
  asm("v_cvt_pk_bf16_f32 %0, %1, %2" : "=v"(w) : "v"(lo), "v"(hi));
  return w;
}
__device__ __forceinline__ float fexp2(float x) {   // raw v_exp_f32 (log2 domain)
  float r;
  asm("v_exp_f32 %0, %1" : "=v"(r) : "v"(x));
  return r;
}
__device__ __forceinline__ void pl32swap(unsigned& a, unsigned& b) {
  asm volatile("v_permlane32_swap_b32 %0, %1" : "+v"(a), "+v"(b));
}
__device__ __forceinline__ s16x8 frag8(unsigned a, unsigned b, unsigned c, unsigned d) {
  union { unsigned u[4]; s16x8 v; } t;
  t.u[0] = a; t.u[1] = b; t.u[2] = c; t.u[3] = d;
  return t.v;
}
__device__ __forceinline__ f32x16 mfma32(s16x8 a, s16x8 b, f32x16 c) {
  return __builtin_amdgcn_mfma_f32_32x32x16_bf16(a, b, c, 0, 0, 0);
}

__device__ __forceinline__ void gload_lds16(const u16* g, u16* lds) {
  __builtin_amdgcn_global_load_lds(
      (const __attribute__((address_space(1))) unsigned int*)g,
      (__attribute__((address_space(3))) unsigned int*)lds, 16, 0, 0);
}

// ---------------- prepass kernels ----------------

__global__ __launch_bounds__(256) void cvt_f32_bf16(const float* __restrict__ x,
                                                    u16* __restrict__ y, int n4) {
  int i = blockIdx.x * 256 + threadIdx.x;
  if (i < n4) {
    f32x4 v = *(const f32x4*)&x[(size_t)i * 4];
    s16x4 o;
    o[0] = (short)f2bf(v[0]); o[1] = (short)f2bf(v[1]);
    o[2] = (short)f2bf(v[2]); o[3] = (short)f2bf(v[3]);
    *(s16x4*)&y[(size_t)i * 4] = o;
  }
}

// W[K][N] f32 -> WT[N][K] bf16
__global__ __launch_bounds__(256) void transpose_w_bf16(const float* __restrict__ W,
                                                        u16* __restrict__ WT,
                                                        int K, int N) {
  __shared__ float tile[32][33];
  const int n0 = blockIdx.x * 32, k0 = blockIdx.y * 32;
  const int tx = threadIdx.x & 31, ty = threadIdx.x >> 5;
#pragma unroll
  for (int i = 0; i < 32; i += 8)
    tile[ty + i][tx] = W[(size_t)(k0 + ty + i) * N + (n0 + tx)];
  __syncthreads();
#pragma unroll
  for (int i = 0; i < 32; i += 8)
    WT[(size_t)(n0 + ty + i) * K + (k0 + tx)] = f2bf(tile[tx][ty + i]);
}

// v_ws [bh][s][d] bf16 -> vT_ws [bh][d][s] bf16, 64x64 LDS tiles
__global__ __launch_bounds__(256) void transpose_v(const u16* __restrict__ v,
                                                   u16* __restrict__ vT) {
  __shared__ u16 tile[64][72];   // +8 pad
  const int bh = blockIdx.y;
  const int s0 = blockIdx.x * 64;
  const int tr = threadIdx.x >> 2, tc = (threadIdx.x & 3) * 16;
  const u16* src = v + (size_t)bh * 131072u + (size_t)(s0 + tr) * 64 + tc;
  *(s16x8*)&tile[tr][tc] = *(const s16x8*)src;
  *(s16x8*)&tile[tr][tc + 8] = *(const s16x8*)(src + 8);
  __syncthreads();
  u16 o[16];
#pragma unroll
  for (int x = 0; x < 16; x++) o[x] = tile[tc + x][tr];
  u16* dst = vT + (size_t)bh * 131072u + (size_t)tr * 2048 + s0 + tc;
  *(s16x8*)dst = *(s16x8*)&o[0];
  *(s16x8*)(dst + 8) = *(s16x8*)&o[8];
}

// bias -> packed triangular f32 table in the 32x32 MFMA C/D register layout, *LOG2E,
// causal mask folded as -1e30. Entry (q32,kt,t,lane,reg):
//   q = q32*32 + (lane&31), k = kt*64 + t*32 + (reg&3) + 8*(reg>>2) + 4*(lane>>5)
// Packed pair index boff(q32) = (h + (q32&1))*(h+1), h = q32>>1; kt <= h.  ~8.65MB.
__global__ __launch_bounds__(128) void bias_tile(const float* __restrict__ B,
                                                 float* __restrict__ T) {
  const int kt = blockIdx.x;      // 0..31
  const int q32 = blockIdx.y;     // 0..63
  if (kt > (q32 >> 1)) return;
  const int t = threadIdx.x >> 6, lane = threadIdx.x & 63;
  const int hh = q32 >> 1;
  const size_t boff = (size_t)(hh + (q32 & 1)) * (hh + 1);
  const int q = q32 * 32 + (lane & 31);
  const int kb = kt * 64 + t * 32 + 4 * (lane >> 5);
  float v[16];
#pragma unroll
  for (int r = 0; r < 16; r++) {
    const int k = kb + (r & 3) + 8 * (r >> 2);
    v[r] = (k <= q) ? B[(size_t)q * 2048 + k] * LOG2E : -1e30f;
  }
  float* dst = T + (boff + kt) * 2048 + t * 1024 + (size_t)lane * 16;
  *(f32x4*)dst = *(f32x4*)&v[0];
  *(f32x4*)(dst + 4) = *(f32x4*)&v[4];
  *(f32x4*)(dst + 8) = *(f32x4*)&v[8];
  *(f32x4*)(dst + 12) = *(f32x4*)&v[12];
}

// ---------------- GEMM: C[M][N] = A[M][K] * BT[N][K]^T + bias ----------------
// 128^2 tile, BK=32, 4 waves, double-buffered (round-8 verified).

template <int MODE>
__global__ __launch_bounds__(256) void gemm_bt(
    const u16* __restrict__ A, const u16* __restrict__ BT,
    const float* __restrict__ bias, float* __restrict__ outF,
    u16* __restrict__ q_ws, u16* __restrict__ k_ws, u16* __restrict__ v_ws,
    int M, int N, int K) {
  __shared__ u16 As[2][128 * 32];
  __shared__ u16 Bs[2][128 * 32];
  const int nwg = gridDim.x * gridDim.y;
  int flat = blockIdx.y * gridDim.x + blockIdx.x;
  flat = (flat & 7) * (nwg >> 3) + (flat >> 3);
  const int m0 = (flat / gridDim.x) * 128, n0 = (flat % gridDim.x) * 128;
  const int tid = threadIdx.x;
  const int wid = tid >> 6, lane = tid & 63;
  const int c = lane & 15, hi = lane >> 4;
  const int wm = wid >> 1, wn = wid & 1;
  const int srow = lane >> 2;
  const int skp = (lane & 3) * 8;

  f32x4 acc[4][4] = {};

#define STG(SLOT, K0)                                                         \
  {                                                                           \
    _Pragma("unroll")                                                         \
    for (int t = 0; t < 2; t++) {                                             \
      const int rowl = wid * 32 + t * 16;                                     \
      gload_lds16(&A[(size_t)(m0 + rowl + srow) * K + (K0) + skp],            \
                  &As[SLOT][rowl * 32]);                                      \
      gload_lds16(&BT[(size_t)(n0 + rowl + srow) * K + (K0) + skp],           \
                  &Bs[SLOT][rowl * 32]);                                      \
    }                                                                         \
  }

  STG(0, 0);
  __syncthreads();

  int bufi = 0;
  for (int k0 = 0; k0 < K; k0 += 32) {
    if (k0 + 32 < K) {
      if (bufi) { STG(0, k0 + 32); } else { STG(1, k0 + 32); }
    }
    s16x8 af[4], bfr[4];
#pragma unroll
    for (int i = 0; i < 4; i++)
      af[i] = *(const s16x8*)&As[bufi][(wm * 64 + i * 16 + c) * 32 + hi * 8];
#pragma unroll
    for (int i = 0; i < 4; i++)
      bfr[i] = *(const s16x8*)&Bs[bufi][(wn * 64 + i * 16 + c) * 32 + hi * 8];
    __builtin_amdgcn_s_setprio(1);
#pragma unroll
    for (int i = 0; i < 4; i++)
#pragma unroll
      for (int j = 0; j < 4; j++)
        acc[i][j] = __builtin_amdgcn_mfma_f32_16x16x32_bf16(af[i], bfr[j], acc[i][j], 0, 0, 0);
    __builtin_amdgcn_s_setprio(0);
    __syncthreads();
    bufi ^= 1;
  }
#undef STG

  if (MODE == 1) {
#pragma unroll
    for (int i = 0; i < 4; i++) {
#pragma unroll
      for (int j = 0; j < 4; j++) {
        const int col = n0 + wn * 64 + j * 16 + c;
        const int rb = m0 + wm * 64 + i * 16 + hi * 4;
        const float bv = bias[col];
#pragma unroll
        for (int u = 0; u < 4; u++)
          outF[(size_t)(rb + u) * N + col] = acc[i][j][u] + bv;
      }
    }
  } else {
    const int which = n0 >> 10;    // block-uniform: 0=q 1=k 2=v
#pragma unroll
    for (int i = 0; i < 4; i++) {
#pragma unroll
      for (int j = 0; j < 4; j++) {
        const int col = n0 + wn * 64 + j * 16 + c;
        const int rb = m0 + wm * 64 + i * 16 + hi * 4;
        const float bv = bias[col];
        const int h = (col >> 6) & 15, d = col & 63;
#pragma unroll
        for (int u = 0; u < 4; u++) {
          const int r = rb + u;
          const int b = r >> 11, s = r & 2047;
          const size_t idx = (size_t)(b * 16 + h) * 131072u + (size_t)s * 64 + d;
          const float v = acc[i][j][u] + bv;
          if (which == 0) {
            q_ws[idx] = f2bf(v * QSCALE);     // fold 1/sqrt(hd) * LOG2E
          } else if (which == 1) {
            outF[4194304u + idx] = v;
            k_ws[idx] = f2bf(v);
          } else {
            outF[8388608u + idx] = v;
            v_ws[idx] = f2bf(v);              // row-major; transposed later
          }
        }
      }
    }
  }
}

// ---------------- fused causal attention ----------------
// 512 blocks, each handles q-tiles {jp, 31-jp} sequentially => uniform 33 tile-units
// per block (kills intra-CU tail imbalance). 4 waves = (pq q-subtile, par k-half).
// Swapped QK^T, in-register softmax, f32 bias C-init (prefetched), reg-q merge.

__global__ __launch_bounds__(256, 4) void attn_fused(
    const u16* __restrict__ q_ws, const u16* __restrict__ k_ws,
    const u16* __restrict__ vT_ws, const float* __restrict__ biasT,
    u16* __restrict__ ctx) {
  __shared__ u16 Ks[2][64 * 64];
  __shared__ u16 Vs[2][64 * 64];

  const int id = blockIdx.x;                     // 0..511
  const int bh = (id & 7) * 4 + ((id >> 3) & 3); // 4 heads per XCD (L2-fit)
  const int jp = id >> 5;                        // 0..15

  const int wid = threadIdx.x >> 6, lane = threadIdx.x & 63;
  const int pq = wid >> 1, par = wid & 1;
  const int l31 = lane & 31, hi5 = lane >> 5;
  const int swz = l31 & 7;
  const int arow = par * 32 + l31;
  const int sl_r = lane >> 3, sl_c = lane & 7;

  const u16* qh = q_ws + (size_t)bh * 131072u;
  const u16* kh = k_ws + (size_t)bh * 131072u;
  const u16* vh = vT_ws + (size_t)bh * 131072u;
  const int b = bh >> 4, h = bh & 15;

#define STAGE(BUF, N0)                                                        \
  {                                                                           \
    _Pragma("unroll")                                                         \
    for (int t = 0; t < 2; t++) {                                             \
      const int rb = wid * 16 + t * 8;                                        \
      const int r = rb + sl_r;                                                \
      gload_lds16(&kh[(size_t)((N0) + r) * 64 + ((sl_c ^ (r & 7)) * 8)],      \
                  &Ks[BUF][rb * 64]);                                         \
      gload_lds16(&vh[(size_t)r * 2048 + (N0) + ((sl_c ^ (r & 7)) * 8)],      \
                  &Vs[BUF][rb * 64]);                                         \
    }                                                                         \
  }

#pragma unroll 1
  for (int half = 0; half < 2; half++) {
    const int qblk = half ? (31 - jp) : jp;
    const int qrow0 = qblk * 64 + pq * 32;
    const int nkt = qblk + 1;

    s16x8 qf[4];
#pragma unroll
    for (int s = 0; s < 4; s++)
      qf[s] = *(const s16x8*)&qh[(size_t)(qrow0 + l31) * 64 + s * 16 + hi5 * 8];

    const int q32 = qblk * 2 + pq;
    const int hh = q32 >> 1;
    const size_t boff = (size_t)(hh + (q32 & 1)) * (hh + 1);
    const float* bb = biasT + boff * 2048 + (size_t)par * 1024 + (size_t)lane * 16;

    f32x16 o0 = {}, o1 = {};
    float mrow = -1e30f, lpart = 0.f;

    STAGE(0, 0);
    __syncthreads();

    int buf = 0;
    f32x4 bc0 = *(const f32x4*)(bb);
    f32x4 bc1 = *(const f32x4*)(bb + 4);
    f32x4 bc2 = *(const f32x4*)(bb + 8);
    f32x4 bc3 = *(const f32x4*)(bb + 12);

    for (int kt = 0; kt < nkt; ++kt) {
      if (kt + 1 < nkt) {
        if (buf) { STAGE(0, kt * 64 + 64); } else { STAGE(1, kt * 64 + 64); }
      }
      const float* bn = bb + (size_t)((kt + 1 < nkt) ? kt + 1 : kt) * 2048;
      const f32x4 bn0 = *(const f32x4*)(bn);
      const f32x4 bn1 = *(const f32x4*)(bn + 4);
      const f32x4 bn2 = *(const f32x4*)(bn + 8);
      const f32x4 bn3 = *(const f32x4*)(bn + 12);

      // bias as C-init (log2 domain, mask folded)
      f32x16 s0;
#pragma unroll
      for (int r = 0; r < 4; r++) {
        s0[r] = bc0[r]; s0[r + 4] = bc1[r];
        s0[r + 8] = bc2[r]; s0[r + 12] = bc3[r];
      }

      const u16* ksb = &Ks[buf][0];
      __builtin_amdgcn_s_setprio(1);
#pragma unroll
      for (int s = 0; s < 4; s++) {
        const int chq = ((s * 2 + hi5) ^ swz) * 8;
        const s16x8 a0 = *(const s16x8*)&ksb[arow * 64 + chq];
        s0 = mfma32(a0, qf[s], s0);
      }
      __builtin_amdgcn_s_setprio(0);

      float t0 = fmaxf(fmaxf(s0[0], s0[1]), fmaxf(s0[2], s0[3]));
      float t1 = fmaxf(fmaxf(s0[4], s0[5]), fmaxf(s0[6], s0[7]));
      float t2 = fmaxf(fmaxf(s0[8], s0[9]), fmaxf(s0[10], s0[11]));
      float t3 = fmaxf(fmaxf(s0[12], s0[13]), fmaxf(s0[14], s0[15]));
      float tm = fmaxf(fmaxf(t0, t1), fmaxf(t2, t3));
      tm = fmaxf(tm, __shfl_xor(tm, 32));

      if (__any(tm > mrow + 8.f)) {            // deferred rescale (THR=8, log2 units)
        const float nm = fmaxf(mrow, tm);
        const float al = fexp2(mrow - nm);
        mrow = nm;
        lpart *= al;
#pragma unroll
        for (int r = 0; r < 16; r++) { o0[r] *= al; o1[r] *= al; }
      }

      float a0s = 0.f, a1s = 0.f;
#pragma unroll
      for (int r = 0; r < 8; r++) {
        s0[r] = fexp2(s0[r] - mrow);         a0s += s0[r];
        s0[r + 8] = fexp2(s0[r + 8] - mrow); a1s += s0[r + 8];
      }
      lpart += a0s + a1s;

      unsigned wv0 = cvtpk(s0[0], s0[1]),   wv1 = cvtpk(s0[2], s0[3]);
      unsigned wv2 = cvtpk(s0[4], s0[5]),   wv3 = cvtpk(s0[6], s0[7]);
      unsigned wv4 = cvtpk(s0[8], s0[9]),   wv5 = cvtpk(s0[10], s0[11]);
      unsigned wv6 = cvtpk(s0[12], s0[13]), wv7 = cvtpk(s0[14], s0[15]);
      pl32swap(wv0, wv2); pl32swap(wv1, wv3);
      pl32swap(wv4, wv6); pl32swap(wv5, wv7);

      const u16* vsb = &Vs[buf][0];
      __builtin_amdgcn_s_setprio(1);
#pragma unroll
      for (int hf = 0; hf < 2; hf++) {
        const s16x8 pa = hf ? frag8(wv4, wv5, wv6, wv7) : frag8(wv0, wv1, wv2, wv3);
        const int s = par * 2 + hf;
        const int chv = ((s * 2 + hi5) ^ swz) * 8;
        const s16x8 v0 = *(const s16x8*)&vsb[l31 * 64 + chv];
        const s16x8 v1 = *(const s16x8*)&vsb[(32 + l31) * 64 + chv];
        o0 = mfma32(pa, v0, o0);
        o1 = mfma32(pa, v1, o1);
      }
      __builtin_amdgcn_s_setprio(0);

      __syncthreads();
      buf ^= 1;
      bc0 = bn0; bc1 = bn1; bc2 = bn2; bc3 = bn3;
    }

    // combine hi5 halves (disjoint k-rows within this parity's half)
    lpart += __shfl_xor(lpart, 32);

    // k-half merge per (q=reg, d=lane) — reg-q space
    float* obuf = (float*)&Ks[0][0];     // [32 reg][128 slot] f32 = 16KB
    float2* mlb = (float2*)&Vs[0][0];    // [(par*2+pq)*64 + q] -> (m, l)

    __syncthreads();
    if (hi5 == 0) mlb[(par * 2 + pq) * 64 + l31] = make_float2(mrow, lpart);
    if (par == 1) {
      const int slot = pq * 64 + lane;
#pragma unroll
      for (int r = 0; r < 16; r++) {
        obuf[r * 128 + slot] = o0[r];
        obuf[(16 + r) * 128 + slot] = o1[r];
      }
    }
    __syncthreads();
    if (par == 0) {
      const int slot = pq * 64 + lane;
#pragma unroll
      for (int r = 0; r < 16; r++) {
        const int qloc = (r & 3) + 8 * (r >> 2) + 4 * hi5;
        const float2 Aml = mlb[pq * 64 + qloc];
        const float2 Bml = mlb[(2 + pq) * 64 + qloc];
        const float mm = fmaxf(Aml.x, Bml.x);
        const float fa = fexp2(Aml.x - mm), fb = fexp2(Bml.x - mm);
        const float inv = __builtin_amdgcn_rcpf(Aml.y * fa + Bml.y * fb);
        const float om0 = (o0[r] * fa + obuf[r * 128 + slot] * fb) * inv;
        const float om1 = (o1[r] * fa + obuf[(16 + r) * 128 + slot] * fb) * inv;
        const int tok = b * 2048 + qrow0 + qloc;
        ctx[(size_t)tok * 1024 + h * 64 + l31] = f2bf(om0);
        ctx[(size_t)tok * 1024 + h * 64 + 32 + l31] = f2bf(om1);
      }
    }
    __syncthreads();   // obuf/mlb reads done before next half restages Ks/Vs
  }
#undef STAGE
}

// ---------------- launch ----------------

extern "C" void kernel_launch(void* const* d_in, const int* in_sizes, int n_in,
                              void* d_out, int out_size, void* d_ws, size_t ws_size,
                              hipStream_t stream) {
  const float* hs        = (const float*)d_in[0];  // [2,2048,1024]
  const float* c_attn_w  = (const float*)d_in[1];  // [1024,3072]
  const float* c_attn_b  = (const float*)d_in[2];  // [3072]
  const float* attn_bias = (const float*)d_in[3];  // [2048,2048]
  const float* c_proj_w  = (const float*)d_in[4];  // [1024,1024]
  const float* c_proj_b  = (const float*)d_in[5];  // [1024]
  float* out = (float*)d_out;  // out(4M) | k(4M) | v(4M)

  uint8_t* ws = (uint8_t*)d_ws;
  u16* hsb    = (u16*)(ws + 0);           // 8MB [4096][1024] bf16
  u16* wqkvT  = (u16*)(ws + 8388608u);    // 6MB [3072][1024] bf16
  u16* wprojT = (u16*)(ws + 14680064u);   // 2MB [1024][1024] bf16
  u16* q_ws   = (u16*)(ws + 16777216u);   // 8MB [B,H,S,hd] bf16 (q * QSCALE)
  u16* k_ws   = (u16*)(ws + 25165824u);   // 8MB [B,H,S,hd] bf16
  u16* vT_ws  = (u16*)(ws + 33554432u);   // 8MB [B,H,hd,S] bf16
  u16* ctx    = (u16*)(ws + 41943040u);   // 8MB [4096][1024] bf16 (also v_ws row-major)
  u16* v_ws   = ctx;                      // v row-major staging; consumed by transpose_v
  float* biasT = (float*)(ws + 0);        // 8.65MB f32 table overlays dead hsb+wqkvT head

  cvt_f32_bf16<<<4096, 256, 0, stream>>>(hs, hsb, 1048576);
  transpose_w_bf16<<<dim3(96, 32), 256, 0, stream>>>(c_attn_w, wqkvT, 1024, 3072);
  transpose_w_bf16<<<dim3(32, 32), 256, 0, stream>>>(c_proj_w, wprojT, 1024, 1024);

  gemm_bt<0><<<dim3(24, 32), 256, 0, stream>>>(hsb, wqkvT, c_attn_b, out,
                                               q_ws, k_ws, v_ws, 4096, 3072, 1024);

  transpose_v<<<dim3(32, 32), 256, 0, stream>>>(v_ws, vT_ws);

  bias_tile<<<dim3(32, 64), 128, 0, stream>>>(attn_bias, biasT);

  attn_fused<<<dim3(512), 256, 0, stream>>>(q_ws, k_ws, vT_ws, biasT, ctx);

  gemm_bt<1><<<dim3(8, 32), 256, 0, stream>>>(ctx, wprojT, c_proj_b, out,
                                              (u16*)nullptr, (u16*)nullptr, (u16*)nullptr,
                                              4096, 1024, 1024);
}

// Round 11
// 128.623 us; speedup vs baseline: 1.1524x; 1.1183x over previous
//
#include <hip/hip_runtime.h>
#include <hip/hip_bf16.h>
#include <stdint.h>

// GPT-2 prefill attention: B=2, S=2048, D=1024, H=16, hd=64.
// cvt/transpose prepass -> QKV GEMM (128^2 double-buffered) -> v transpose
// -> bias tiling (bf16) -> flash attn (longest-first dispatch) -> proj GEMM.

typedef __attribute__((ext_vector_type(4))) float f32x4;
typedef __attribute__((ext_vector_type(16))) float f32x16;
typedef __attribute__((ext_vector_type(8))) short s16x8;
typedef __attribute__((ext_vector_type(4))) short s16x4;
typedef unsigned short u16;

#define LOG2E 1.4426950408889634f
#define QSCALE 0.18033688011112042f  // 0.125 * LOG2E

__device__ __forceinline__ u16 f2bf(float f) {
  unsigned w;
  asm("v_cvt_pk_bf16_f32 %0, %1, %2" : "=v"(w) : "v"(f), "v"(f));
  return (u16)w;
}
__device__ __forceinline__ unsigned cvtpk(float lo, float hi) {
  unsigned w;
  asm("v_cvt_pk_bf16_f32 %0, %1, %2" : "=v"(w) : "v"(lo), "v"(hi));
  return w;
}
__device__ __forceinline__ float bf2f(u16 h) {
  unsigned int x = ((unsigned int)h) << 16;
  return __builtin_bit_cast(float, x);
}
__device__ __forceinline__ float fexp2(float x) {   // raw v_exp_f32 (log2 domain)
  float r;
  asm("v_exp_f32 %0, %1" : "=v"(r) : "v"(x));
  return r;
}
__device__ __forceinline__ void pl32swap(unsigned& a, unsigned& b) {
  asm volatile("v_permlane32_swap_b32 %0, %1" : "+v"(a), "+v"(b));
}
__device__ __forceinline__ s16x8 frag8(unsigned a, unsigned b, unsigned c, unsigned d) {
  union { unsigned u[4]; s16x8 v; } t;
  t.u[0] = a; t.u[1] = b; t.u[2] = c; t.u[3] = d;
  return t.v;
}
__device__ __forceinline__ f32x16 mfma32(s16x8 a, s16x8 b, f32x16 c) {
  return __builtin_amdgcn_mfma_f32_32x32x16_bf16(a, b, c, 0, 0, 0);
}

__device__ __forceinline__ void gload_lds16(const u16* g, u16* lds) {
  __builtin_amdgcn_global_load_lds(
      (const __attribute__((address_space(1))) unsigned int*)g,
      (__attribute__((address_space(3))) unsigned int*)lds, 16, 0, 0);
}

// ---------------- prepass kernels ----------------

__global__ __launch_bounds__(256) void cvt_f32_bf16(const float* __restrict__ x,
                                                    u16* __restrict__ y, int n4) {
  int i = blockIdx.x * 256 + threadIdx.x;
  if (i < n4) {
    f32x4 v = *(const f32x4*)&x[(size_t)i * 4];
    s16x4 o;
    o[0] = (short)f2bf(v[0]); o[1] = (short)f2bf(v[1]);
    o[2] = (short)f2bf(v[2]); o[3] = (short)f2bf(v[3]);
    *(s16x4*)&y[(size_t)i * 4] = o;
  }
}

// W[K][N] f32 -> WT[N][K] bf16
__global__ __launch_bounds__(256) void transpose_w_bf16(const float* __restrict__ W,
                                                        u16* __restrict__ WT,
                                                        int K, int N) {
  __shared__ float tile[32][33];
  const int n0 = blockIdx.x * 32, k0 = blockIdx.y * 32;
  const int tx = threadIdx.x & 31, ty = threadIdx.x >> 5;
#pragma unroll
  for (int i = 0; i < 32; i += 8)
    tile[ty + i][tx] = W[(size_t)(k0 + ty + i) * N + (n0 + tx)];
  __syncthreads();
#pragma unroll
  for (int i = 0; i < 32; i += 8)
    WT[(size_t)(n0 + ty + i) * K + (k0 + tx)] = f2bf(tile[tx][ty + i]);
}

// v_ws [bh][s][d] bf16 -> vT_ws [bh][d][s] bf16, 64x64 LDS tiles
__global__ __launch_bounds__(256) void transpose_v(const u16* __restrict__ v,
                                                   u16* __restrict__ vT) {
  __shared__ u16 tile[64][72];   // +8 pad
  const int bh = blockIdx.y;
  const int s0 = blockIdx.x * 64;
  const int tr = threadIdx.x >> 2, tc = (threadIdx.x & 3) * 16;
  const u16* src = v + (size_t)bh * 131072u + (size_t)(s0 + tr) * 64 + tc;
  *(s16x8*)&tile[tr][tc] = *(const s16x8*)src;
  *(s16x8*)&tile[tr][tc + 8] = *(const s16x8*)(src + 8);
  __syncthreads();
  u16 o[16];
#pragma unroll
  for (int x = 0; x < 16; x++) o[x] = tile[tc + x][tr];
  u16* dst = vT + (size_t)bh * 131072u + (size_t)tr * 2048 + s0 + tc;
  *(s16x8*)dst = *(s16x8*)&o[0];
  *(s16x8*)(dst + 8) = *(s16x8*)&o[8];
}

// bias -> packed triangular bf16 table in the 32x32 MFMA C/D register layout, *LOG2E,
// causal mask folded as -inf. Entry (q32,kt,t,lane,reg):
//   q = q32*32 + (lane&31), k = kt*64 + t*32 + (reg&3) + 8*(reg>>2) + 4*(lane>>5)
// Packed pair index boff(q32) = (h + (q32&1))*(h+1), h = q32>>1; kt <= h.
__global__ __launch_bounds__(128) void bias_tile(const float* __restrict__ B,
                                                 u16* __restrict__ T) {
  const int kt = blockIdx.x;      // 0..31
  const int q32 = blockIdx.y;     // 0..63
  if (kt > (q32 >> 1)) return;
  const int t = threadIdx.x >> 6, lane = threadIdx.x & 63;
  const int hh = q32 >> 1;
  const size_t boff = (size_t)(hh + (q32 & 1)) * (hh + 1);
  const int q = q32 * 32 + (lane & 31);
  const int kb = kt * 64 + t * 32 + 4 * (lane >> 5);
  u16 v[16];
#pragma unroll
  for (int r = 0; r < 16; r++) {
    const int k = kb + (r & 3) + 8 * (r >> 2);
    v[r] = (k <= q) ? f2bf(B[(size_t)q * 2048 + k] * LOG2E) : (u16)0xFF80;
  }
  u16* dst = T + (boff + kt) * 2048 + t * 1024 + (size_t)lane * 16;
  *(s16x8*)dst = *(s16x8*)&v[0];
  *(s16x8*)(dst + 8) = *(s16x8*)&v[8];
}

// ---------------- GEMM: C[M][N] = A[M][K] * BT[N][K]^T + bias ----------------
// 128^2 tile, BK=32, 4 waves, double-buffered (round-8 verified).

template <int MODE>
__global__ __launch_bounds__(256) void gemm_bt(
    const u16* __restrict__ A, const u16* __restrict__ BT,
    const float* __restrict__ bias, float* __restrict__ outF,
    u16* __restrict__ q_ws, u16* __restrict__ k_ws, u16* __restrict__ v_ws,
    int M, int N, int K) {
  __shared__ u16 As[2][128 * 32];
  __shared__ u16 Bs[2][128 * 32];
  const int nwg = gridDim.x * gridDim.y;
  int flat = blockIdx.y * gridDim.x + blockIdx.x;
  flat = (flat & 7) * (nwg >> 3) + (flat >> 3);
  const int m0 = (flat / gridDim.x) * 128, n0 = (flat % gridDim.x) * 128;
  const int tid = threadIdx.x;
  const int wid = tid >> 6, lane = tid & 63;
  const int c = lane & 15, hi = lane >> 4;
  const int wm = wid >> 1, wn = wid & 1;
  const int srow = lane >> 2;
  const int skp = (lane & 3) * 8;

  f32x4 acc[4][4] = {};

#define STG(SLOT, K0)                                                         \
  {                                                                           \
    _Pragma("unroll")                                                         \
    for (int t = 0; t < 2; t++) {                                             \
      const int rowl = wid * 32 + t * 16;                                     \
      gload_lds16(&A[(size_t)(m0 + rowl + srow) * K + (K0) + skp],            \
                  &As[SLOT][rowl * 32]);                                      \
      gload_lds16(&BT[(size_t)(n0 + rowl + srow) * K + (K0) + skp],           \
                  &Bs[SLOT][rowl * 32]);                                      \
    }                                                                         \
  }

  STG(0, 0);
  __syncthreads();

  int bufi = 0;
  for (int k0 = 0; k0 < K; k0 += 32) {
    if (k0 + 32 < K) {
      if (bufi) { STG(0, k0 + 32); } else { STG(1, k0 + 32); }
    }
    s16x8 af[4], bfr[4];
#pragma unroll
    for (int i = 0; i < 4; i++)
      af[i] = *(const s16x8*)&As[bufi][(wm * 64 + i * 16 + c) * 32 + hi * 8];
#pragma unroll
    for (int i = 0; i < 4; i++)
      bfr[i] = *(const s16x8*)&Bs[bufi][(wn * 64 + i * 16 + c) * 32 + hi * 8];
    __builtin_amdgcn_s_setprio(1);
#pragma unroll
    for (int i = 0; i < 4; i++)
#pragma unroll
      for (int j = 0; j < 4; j++)
        acc[i][j] = __builtin_amdgcn_mfma_f32_16x16x32_bf16(af[i], bfr[j], acc[i][j], 0, 0, 0);
    __builtin_amdgcn_s_setprio(0);
    __syncthreads();
    bufi ^= 1;
  }
#undef STG

  if (MODE == 1) {
#pragma unroll
    for (int i = 0; i < 4; i++) {
#pragma unroll
      for (int j = 0; j < 4; j++) {
        const int col = n0 + wn * 64 + j * 16 + c;
        const int rb = m0 + wm * 64 + i * 16 + hi * 4;
        const float bv = bias[col];
#pragma unroll
        for (int u = 0; u < 4; u++)
          outF[(size_t)(rb + u) * N + col] = acc[i][j][u] + bv;
      }
    }
  } else {
    const int which = n0 >> 10;    // block-uniform: 0=q 1=k 2=v
#pragma unroll
    for (int i = 0; i < 4; i++) {
#pragma unroll
      for (int j = 0; j < 4; j++) {
        const int col = n0 + wn * 64 + j * 16 + c;
        const int rb = m0 + wm * 64 + i * 16 + hi * 4;
        const float bv = bias[col];
        const int h = (col >> 6) & 15, d = col & 63;
#pragma unroll
        for (int u = 0; u < 4; u++) {
          const int r = rb + u;
          const int b = r >> 11, s = r & 2047;
          const size_t idx = (size_t)(b * 16 + h) * 131072u + (size_t)s * 64 + d;
          const float v = acc[i][j][u] + bv;
          if (which == 0) {
            q_ws[idx] = f2bf(v * QSCALE);     // fold 1/sqrt(hd) * LOG2E
          } else if (which == 1) {
            outF[4194304u + idx] = v;
            k_ws[idx] = f2bf(v);
          } else {
            outF[8388608u + idx] = v;
            v_ws[idx] = f2bf(v);              // row-major; transposed later
          }
        }
      }
    }
  }
}

// ---------------- fused causal attention ----------------
// 1024 blocks, LONGEST-FIRST dispatch (LPT: qblk = 31 - (id>>5); HW backfill packs
// short blocks into the tail). bh in low 5 bits: 4 heads per XCD (L2-fit).
// 4 waves = (pq q-subtile, par k-half). Swapped QK^T, in-register softmax,
// bf16 bias C-init (prefetched), reg-q-space k-half merge.

__global__ __launch_bounds__(256, 4) void attn_fused(
    const u16* __restrict__ q_ws, const u16* __restrict__ k_ws,
    const u16* __restrict__ vT_ws, const u16* __restrict__ biasT,
    u16* __restrict__ ctx) {
  __shared__ u16 Ks[2][64 * 64];
  __shared__ u16 Vs[2][64 * 64];

  const int id = blockIdx.x;
  const int bh = (id & 7) * 4 + ((id >> 3) & 3);
  const int qblk = 31 - (id >> 5);               // LPT: longest blocks dispatch first

  const int wid = threadIdx.x >> 6, lane = threadIdx.x & 63;
  const int pq = wid >> 1, par = wid & 1;
  const int l31 = lane & 31, hi5 = lane >> 5;
  const int qrow0 = qblk * 64 + pq * 32;

  const u16* qh = q_ws + (size_t)bh * 131072u;
  const u16* kh = k_ws + (size_t)bh * 131072u;
  const u16* vh = vT_ws + (size_t)bh * 131072u;

  s16x8 qf[4];
#pragma unroll
  for (int s = 0; s < 4; s++)
    qf[s] = *(const s16x8*)&qh[(size_t)(qrow0 + l31) * 64 + s * 16 + hi5 * 8];

  const int q32 = qblk * 2 + pq;
  const int hh = q32 >> 1;
  const size_t boff = (size_t)(hh + (q32 & 1)) * (hh + 1);
  const u16* bbase = biasT + boff * 2048 + (size_t)par * 1024 + (size_t)lane * 16;

  const int sl_r = lane >> 3, sl_c = lane & 7;

  f32x16 o0 = {}, o1 = {};
  float mrow = -1e30f, lpart = 0.f;

#define STAGE(BUF, N0)                                                        \
  {                                                                           \
    _Pragma("unroll")                                                         \
    for (int t = 0; t < 2; t++) {                                             \
      const int rb = wid * 16 + t * 8;                                        \
      const int r = rb + sl_r;                                                \
      gload_lds16(&kh[(size_t)((N0) + r) * 64 + ((sl_c ^ (r & 7)) * 8)],      \
                  &Ks[BUF][rb * 64]);                                         \
      gload_lds16(&vh[(size_t)r * 2048 + (N0) + ((sl_c ^ (r & 7)) * 8)],      \
                  &Vs[BUF][rb * 64]);                                         \
    }                                                                         \
  }

  STAGE(0, 0);
  __syncthreads();

  int buf = 0;
  const int nkt = qblk + 1;
  const int swz = l31 & 7;
  const int arow = par * 32 + l31;

  s16x8 bc0 = *(const s16x8*)(bbase);
  s16x8 bc1 = *(const s16x8*)(bbase + 8);

  for (int kt = 0; kt < nkt; ++kt) {
    if (kt + 1 < nkt) {
      if (buf) { STAGE(0, kt * 64 + 64); } else { STAGE(1, kt * 64 + 64); }
    }
    const u16* btn = bbase + (size_t)((kt + 1 < nkt) ? kt + 1 : kt) * 2048;
    const s16x8 bn0 = *(const s16x8*)(btn);
    const s16x8 bn1 = *(const s16x8*)(btn + 8);

    f32x16 s0;
#pragma unroll
    for (int r = 0; r < 8; r++) {
      s0[r] = bf2f((u16)bc0[r]);
      s0[r + 8] = bf2f((u16)bc1[r]);
    }

    const u16* ksb = &Ks[buf][0];
    __builtin_amdgcn_s_setprio(1);
#pragma unroll
    for (int s = 0; s < 4; s++) {
      const int chq = ((s * 2 + hi5) ^ swz) * 8;
      const s16x8 a0 = *(const s16x8*)&ksb[arow * 64 + chq];
      s0 = mfma32(a0, qf[s], s0);
    }
    __builtin_amdgcn_s_setprio(0);

    float t0 = fmaxf(fmaxf(s0[0], s0[1]), fmaxf(s0[2], s0[3]));
    float t1 = fmaxf(fmaxf(s0[4], s0[5]), fmaxf(s0[6], s0[7]));
    float t2 = fmaxf(fmaxf(s0[8], s0[9]), fmaxf(s0[10], s0[11]));
    float t3 = fmaxf(fmaxf(s0[12], s0[13]), fmaxf(s0[14], s0[15]));
    float tm = fmaxf(fmaxf(t0, t1), fmaxf(t2, t3));
    tm = fmaxf(tm, __shfl_xor(tm, 32));

    if (__any(tm > mrow + 8.f)) {
      const float nm = fmaxf(mrow, tm);
      const float al = fexp2(mrow - nm);
      mrow = nm;
      lpart *= al;
#pragma unroll
      for (int r = 0; r < 16; r++) { o0[r] *= al; o1[r] *= al; }
    }

    float a0s = 0.f, a1s = 0.f;
#pragma unroll
    for (int r = 0; r < 8; r++) {
      s0[r] = fexp2(s0[r] - mrow);       a0s += s0[r];
      s0[r + 8] = fexp2(s0[r + 8] - mrow); a1s += s0[r + 8];
    }
    lpart += a0s + a1s;

    unsigned wv0 = cvtpk(s0[0], s0[1]),   wv1 = cvtpk(s0[2], s0[3]);
    unsigned wv2 = cvtpk(s0[4], s0[5]),   wv3 = cvtpk(s0[6], s0[7]);
    unsigned wv4 = cvtpk(s0[8], s0[9]),   wv5 = cvtpk(s0[10], s0[11]);
    unsigned wv6 = cvtpk(s0[12], s0[13]), wv7 = cvtpk(s0[14], s0[15]);
    pl32swap(wv0, wv2); pl32swap(wv1, wv3);
    pl32swap(wv4, wv6); pl32swap(wv5, wv7);

    const u16* vsb = &Vs[buf][0];
    __builtin_amdgcn_s_setprio(1);
#pragma unroll
    for (int hf = 0; hf < 2; hf++) {
      const s16x8 pa = hf ? frag8(wv4, wv5, wv6, wv7) : frag8(wv0, wv1, wv2, wv3);
      const int s = par * 2 + hf;
      const int chv = ((s * 2 + hi5) ^ swz) * 8;
      const s16x8 v0 = *(const s16x8*)&vsb[l31 * 64 + chv];
      const s16x8 v1 = *(const s16x8*)&vsb[(32 + l31) * 64 + chv];
      o0 = mfma32(pa, v0, o0);
      o1 = mfma32(pa, v1, o1);
    }
    __builtin_amdgcn_s_setprio(0);

    __syncthreads();
    buf ^= 1;
    bc0 = bn0; bc1 = bn1;
  }
#undef STAGE

  lpart += __shfl_xor(lpart, 32);

  float* obuf = (float*)&Ks[0][0];     // [32 reg][128 slot] f32 = 16KB
  float2* mlb = (float2*)&Vs[0][0];    // [(par*2+pq)*64 + q] -> (m, l)

  __syncthreads();
  if (hi5 == 0) mlb[(par * 2 + pq) * 64 + l31] = make_float2(mrow, lpart);
  if (par == 1) {
    const int slot = pq * 64 + lane;
#pragma unroll
    for (int r = 0; r < 16; r++) {
      obuf[r * 128 + slot] = o0[r];
      obuf[(16 + r) * 128 + slot] = o1[r];
    }
  }
  __syncthreads();
  if (par == 0) {
    const int slot = pq * 64 + lane;
    const int b = bh >> 4, h = bh & 15;
#pragma unroll
    for (int r = 0; r < 16; r++) {
      const int qloc = (r & 3) + 8 * (r >> 2) + 4 * hi5;
      const float2 Aml = mlb[pq * 64 + qloc];
      const float2 Bml = mlb[(2 + pq) * 64 + qloc];
      const float mm = fmaxf(Aml.x, Bml.x);
      const float fa = fexp2(Aml.x - mm), fb = fexp2(Bml.x - mm);
      const float inv = __builtin_amdgcn_rcpf(Aml.y * fa + Bml.y * fb);
      const float om0 = (o0[r] * fa + obuf[r * 128 + slot] * fb) * inv;
      const float om1 = (o1[r] * fa + obuf[(16 + r) * 128 + slot] * fb) * inv;
      const int tok = b * 2048 + qrow0 + qloc;
      ctx[(size_t)tok * 1024 + h * 64 + l31] = f2bf(om0);
      ctx[(size_t)tok * 1024 + h * 64 + 32 + l31] = f2bf(om1);
    }
  }
}

// ---------------- launch ----------------

extern "C" void kernel_launch(void* const* d_in, const int* in_sizes, int n_in,
                              void* d_out, int out_size, void* d_ws, size_t ws_size,
                              hipStream_t stream) {
  const float* hs        = (const float*)d_in[0];  // [2,2048,1024]
  const float* c_attn_w  = (const float*)d_in[1];  // [1024,3072]
  const float* c_attn_b  = (const float*)d_in[2];  // [3072]
  const float* attn_bias = (const float*)d_in[3];  // [2048,2048]
  const float* c_proj_w  = (const float*)d_in[4];  // [1024,1024]
  const float* c_proj_b  = (const float*)d_in[5];  // [1024]
  float* out = (float*)d_out;  // out(4M) | k(4M) | v(4M)

  uint8_t* ws = (uint8_t*)d_ws;
  u16* hsb    = (u16*)(ws + 0);           // 8MB [4096][1024] bf16 (reused for biasT, 4.3MB)
  u16* wqkvT  = (u16*)(ws + 8388608u);    // 6MB [3072][1024] bf16
  u16* wprojT = (u16*)(ws + 14680064u);   // 2MB [1024][1024] bf16
  u16* q_ws   = (u16*)(ws + 16777216u);   // 8MB [B,H,S,hd] bf16 (q * QSCALE)
  u16* k_ws   = (u16*)(ws + 25165824u);   // 8MB [B,H,S,hd] bf16
  u16* vT_ws  = (u16*)(ws + 33554432u);   // 8MB [B,H,hd,S] bf16
  u16* ctx    = (u16*)(ws + 41943040u);   // 8MB [4096][1024] bf16 (also v_ws row-major)
  u16* v_ws   = ctx;                      // v row-major staging; consumed by transpose_v
  u16* biasT  = hsb;                      // overlays hsb after gemm_bt<0>

  cvt_f32_bf16<<<4096, 256, 0, stream>>>(hs, hsb, 1048576);
  transpose_w_bf16<<<dim3(96, 32), 256, 0, stream>>>(c_attn_w, wqkvT, 1024, 3072);
  transpose_w_bf16<<<dim3(32, 32), 256, 0, stream>>>(c_proj_w, wprojT, 1024, 1024);

  gemm_bt<0><<<dim3(24, 32), 256, 0, stream>>>(hsb, wqkvT, c_attn_b, out,
                                               q_ws, k_ws, v_ws, 4096, 3072, 1024);

  transpose_v<<<dim3(32, 32), 256, 0, stream>>>(v_ws, vT_ws);

  bias_tile<<<dim3(32, 64), 128, 0, stream>>>(attn_bias, biasT);

  attn_fused<<<dim3(1024), 256, 0, stream>>>(q_ws, k_ws, vT_ws, biasT, ctx);

  gemm_bt<1><<<dim3(8, 32), 256, 0, stream>>>(ctx, wprojT, c_proj_b, out,
                                              (u16*)nullptr, (u16*)nullptr, (u16*)nullptr,
                                              4096, 1024, 1024);
}